// Round 11
// baseline (246.738 us; speedup 1.0000x reference)
//
#include <hip/hip_runtime.h>

// VectorQuantizer: x [16,1024,256] f32, E [8192,256] f32.
// Outputs concat: quantized_st (4194304 f32) | loss (1) | perplexity (1).
//
// Round 11: r10 GEMM-ized K-loop + r9-style full fusion via per-rowblk spin.
// r10 evidence: score 63us but total 178 (separate merge/gather kernel +
// dispatch ~= 50us overhead). Grid 512 = 64 rowblks x 8 K-partitions is
// fully co-resident (LDS 39KB -> capacity >= 1024 blocks), so the 8 blocks
// of a rowblk sync on a release/acquire ticket and then split the gather
// tail 32 rows each (same 2048-wave gather parallelism, no launch gap).
// Partials: bestp[row][q] u64 = orderable(s_int) || code (u64-min == (s,code)
// lexicographic). Epilogue: 3-op packed min p = enp - (dot<<6), v_min_i32;
// decode s=p>>6, g=p&63 at loop exit (exact ints, same tie-breaks).

#define VQ_N 16384
#define VQ_D 256
#define VQ_K 8192

typedef __attribute__((ext_vector_type(4))) int i32x4;

#define SX 22.0f
#define SEF 1040384.0f               // 127 * 8192
#define ENSCALE 11444224.0           // SX * SEF / 2

__device__ inline int q8(float f, float scale) {
  return __float2int_rn(fminf(fmaxf(f * scale, -127.f), 127.f));
}

__device__ inline void gl_lds16(const void* g, void* l) {
  __builtin_amdgcn_global_load_lds(
      (const __attribute__((address_space(1))) unsigned int*)g,
      (__attribute__((address_space(3))) unsigned int*)l, 16, 0, 0);
}
__device__ inline void gl_lds4(const void* g, void* l) {
  __builtin_amdgcn_global_load_lds(
      (const __attribute__((address_space(1))) unsigned int*)g,
      (__attribute__((address_space(3))) unsigned int*)l, 4, 0, 0);
}

// ---- pack E -> i8 swizzled + en_int + zero hist/tickets/loss ----
__global__ __launch_bounds__(256) void vq_pack(
    const float* __restrict__ E, signed char* __restrict__ Ebs,
    int* __restrict__ en_int, double* __restrict__ loss_sum,
    int* __restrict__ hist, unsigned int* __restrict__ tickrb,
    unsigned int* __restrict__ ticket2) {
  const int gid = blockIdx.x * 256 + threadIdx.x;  // 0..131071
  if (gid < VQ_K) hist[gid] = 0;
  if (gid < 64) tickrb[gid] = 0u;
  if (gid == 0) { *loss_sum = 0.0; *ticket2 = 0u; }
  const int code = gid >> 4;
  const int chunk = gid & 15;
  const float* src = E + (size_t)code * VQ_D + chunk * 16;
  double s = 0.0;
  unsigned int w[4];
#pragma unroll
  for (int v = 0; v < 4; ++v) {
    const float4 f = *(const float4*)(src + v * 4);
    s += (double)f.x * f.x + (double)f.y * f.y + (double)f.z * f.z +
         (double)f.w * f.w;
    const int q0 = q8(f.x, SEF), q1 = q8(f.y, SEF);
    const int q2 = q8(f.z, SEF), q3 = q8(f.w, SEF);
    w[v] = (unsigned)(q0 & 255) | ((unsigned)(q1 & 255) << 8) |
           ((unsigned)(q2 & 255) << 16) | ((unsigned)(q3 & 255) << 24);
  }
  const size_t off =
      ((size_t)(code >> 4) * 16 + chunk) * 256 + (size_t)(code & 15) * 16;
  *(uint4*)(Ebs + off) = make_uint4(w[0], w[1], w[2], w[3]);
#pragma unroll
  for (int m = 1; m <= 8; m <<= 1) s += __shfl_xor(s, m, 64);
  if (chunk == 0) en_int[code] = (int)__double2int_rn(s * ENSCALE);
}

// ---- fused: i8 MFMA score (LDS-staged B) + spin-merge + gather + finalize --
// Grid 512 x 256. Block (rowblk = b>>3, q = b&7): 256 rows x 1024 codes.
__global__ __launch_bounds__(256, 2) void vq_score(
    const float* __restrict__ X, const signed char* __restrict__ Ebs,
    const int* __restrict__ en_int, const float* __restrict__ Ef,
    float* __restrict__ outq, double* __restrict__ loss_sum,
    int* __restrict__ hist, unsigned int* __restrict__ tickrb,
    unsigned int* __restrict__ ticket2,
    unsigned long long* __restrict__ bestp, float* __restrict__ out) {
  __shared__ __align__(16) signed char bbuf[2][16384];  // 2 x 64-code chunks
  __shared__ __align__(16) int enl[1024];
  __shared__ double wsum[4];
  __shared__ double part[256];
  __shared__ int sdone;

  const int tid = threadIdx.x;
  const int wave = tid >> 6;
  const int lane = tid & 63;
  const int quad = lane >> 4;
  const int c15 = lane & 15;
  const int rowblk = blockIdx.x >> 3;
  const int q = blockIdx.x & 7;
  const int r0 = rowblk * 256;
  const int qcode = q * 1024;
  const signed char* ebase = Ebs + (size_t)qcode * 256;

  // Stage en (4 KB) + first B chunk (16 KB). Dest = wave-uniform + lane*size.
  {
    const int* ens = en_int + qcode + wave * 64 + lane;
#pragma unroll
    for (int j = 0; j < 4; ++j)
      gl_lds4(ens + j * 256, enl + j * 256 + wave * 64);
    const signed char* bs = ebase + wave * 1024 + lane * 16;
#pragma unroll
    for (int j = 0; j < 4; ++j)
      gl_lds16(bs + j * 4096, &bbuf[0][j * 4096 + wave * 1024]);
  }

  // A fragments: af[t][m], row r0 + wave*64 + t*16 + c15, k = m*64+quad*16+j.
  i32x4 af[4][4];
#pragma unroll
  for (int t = 0; t < 4; ++t) {
    const float* xr =
        X + (size_t)(r0 + wave * 64 + t * 16 + c15) * VQ_D + quad * 16;
#pragma unroll
    for (int m = 0; m < 4; ++m) {
      const float* p = xr + m * 64;
      i32x4 pk;
#pragma unroll
      for (int v = 0; v < 4; ++v) {
        const float4 f = *(const float4*)(p + v * 4);
        pk[v] = (q8(f.x, SX) & 255) | ((q8(f.y, SX) & 255) << 8) |
                ((q8(f.z, SX) & 255) << 16) | ((q8(f.w, SX) & 255) << 24);
      }
      af[t][m] = pk;
    }
  }

  int best_p[4][4];
#pragma unroll
  for (int t = 0; t < 4; ++t)
#pragma unroll
    for (int r = 0; r < 4; ++r) best_p[t][r] = 0x7fffffff;

#pragma unroll 1
  for (int c = 0; c < 16; ++c) {
    __syncthreads();  // chunk c staged; prior reads of other buffer done
    if (c + 1 < 16) {
      const signed char* bs =
          ebase + (c + 1) * 16384 + wave * 1024 + lane * 16;
#pragma unroll
      for (int j = 0; j < 4; ++j)
        gl_lds16(bs + j * 4096, &bbuf[(c + 1) & 1][j * 4096 + wave * 1024]);
    }
    const signed char* cb = &bbuf[c & 1][0];
#pragma unroll
    for (int g = 0; g < 4; ++g) {
      i32x4 bfr[4];
#pragma unroll
      for (int m = 0; m < 4; ++m)
        bfr[m] = *(const i32x4*)(cb + g * 4096 + m * 1024 + lane * 16);
      const int gidx = c * 4 + g;
      // p = s*64 + gidx = (en*64 + gidx) - (dot<<6); exact int, |p| < 2^31.
      const int enp = (enl[gidx * 16 + c15] << 6) + gidx;
      i32x4 a0 = {0, 0, 0, 0}, a1 = {0, 0, 0, 0};
      i32x4 a2 = {0, 0, 0, 0}, a3 = {0, 0, 0, 0};
#pragma unroll
      for (int m = 0; m < 4; ++m) {
        a0 = __builtin_amdgcn_mfma_i32_16x16x64_i8(af[0][m], bfr[m], a0, 0, 0, 0);
        a1 = __builtin_amdgcn_mfma_i32_16x16x64_i8(af[1][m], bfr[m], a1, 0, 0, 0);
        a2 = __builtin_amdgcn_mfma_i32_16x16x64_i8(af[2][m], bfr[m], a2, 0, 0, 0);
        a3 = __builtin_amdgcn_mfma_i32_16x16x64_i8(af[3][m], bfr[m], a3, 0, 0, 0);
      }
#pragma unroll
      for (int r = 0; r < 4; ++r) {
        best_p[0][r] = min(best_p[0][r], enp - (a0[r] << 6));
        best_p[1][r] = min(best_p[1][r], enp - (a1[r] << 6));
        best_p[2][r] = min(best_p[2][r], enp - (a2[r] << 6));
        best_p[3][r] = min(best_p[3][r], enp - (a3[r] << 6));
      }
    }
  }

  // decode (s, code), u64 lane-reduce over the 16 code-lanes, write partial
#pragma unroll
  for (int t = 0; t < 4; ++t)
#pragma unroll
    for (int r = 0; r < 4; ++r) {
      const int p = best_p[t][r];
      const int s = p >> 6;          // arithmetic: floor(p/64) == s
      const int code = qcode + (p & 63) * 16 + c15;
      unsigned long long v =
          ((unsigned long long)((unsigned)s ^ 0x80000000u) << 32) |
          (unsigned)code;
#pragma unroll
      for (int m = 1; m <= 8; m <<= 1) {
        const unsigned long long ov = __shfl_xor(v, m, 64);
        if (ov < v) v = ov;
      }
      if (c15 == 0) {
        const int row = r0 + wave * 64 + t * 16 + quad * 4 + r;
        bestp[(size_t)row * 8 + q] = v;
      }
    }

  // ---- per-rowblk barrier: all 8 partials visible ----
  __threadfence();
  __syncthreads();
  if (tid == 0) {
    __hip_atomic_fetch_add(&tickrb[rowblk], 1u, __ATOMIC_ACQ_REL,
                           __HIP_MEMORY_SCOPE_AGENT);
    while (__hip_atomic_load(&tickrb[rowblk], __ATOMIC_ACQUIRE,
                             __HIP_MEMORY_SCOPE_AGENT) < 8u)
      __builtin_amdgcn_s_sleep(2);
  }
  __syncthreads();

  // ---- gather tail: this block handles rows r0 + q*32 .. +32 ----
  const int myr0 = r0 + q * 32;
  double lacc = 0.0;
#pragma unroll
  for (int j = 0; j < 8; ++j) {
    const int row = myr0 + wave * 8 + j;
    unsigned long long v =
        (lane < 8) ? bestp[(size_t)row * 8 + lane] : ~0ULL;
#pragma unroll
    for (int m = 1; m <= 4; m <<= 1) {
      const unsigned long long ov = __shfl_xor(v, m, 64);
      if (ov < v) v = ov;
    }
    v = __shfl(v, 0, 64);
    const int k = (int)(v & 0xFFFFFFFFu);
    if (lane == 0)
      __hip_atomic_fetch_add(&hist[k], 1, __ATOMIC_RELAXED,
                             __HIP_MEMORY_SCOPE_AGENT);
    const float4 qv = *(const float4*)(Ef + (size_t)k * VQ_D + lane * 4);
    const float4 xv = *(const float4*)(X + (size_t)row * VQ_D + lane * 4);
    *(float4*)(outq + (size_t)row * VQ_D + lane * 4) = qv;
    const double dx = (double)qv.x - xv.x, dy = (double)qv.y - xv.y;
    const double dz = (double)qv.z - xv.z, dw = (double)qv.w - xv.w;
    lacc += dx * dx + dy * dy + dz * dz + dw * dw;
  }
#pragma unroll
  for (int off = 32; off > 0; off >>= 1) lacc += __shfl_down(lacc, off, 64);
  if (lane == 0) wsum[wave] = lacc;
  __syncthreads();
  if (tid == 0) {
    atomicAdd(loss_sum, wsum[0] + wsum[1] + wsum[2] + wsum[3]);
    __threadfence();
    const unsigned int old = __hip_atomic_fetch_add(
        ticket2, 1u, __ATOMIC_ACQ_REL, __HIP_MEMORY_SCOPE_AGENT);
    sdone = (old == 511u) ? 1 : 0;
  }
  __syncthreads();

  if (sdone) {  // last block: all hist/loss atomics visible
    double s = 0.0;
    for (int k = tid; k < VQ_K; k += 256) {
      const int c = __hip_atomic_load(&hist[k], __ATOMIC_RELAXED,
                                      __HIP_MEMORY_SCOPE_AGENT);
      if (c > 0) {
        const double pr = (double)c * (1.0 / (double)VQ_N);
        s += pr * log(pr + 1e-10);
      }
    }
    part[tid] = s;
    __syncthreads();
    for (int off = 128; off > 0; off >>= 1) {
      if (tid < off) part[tid] += part[tid + off];
      __syncthreads();
    }
    if (tid == 0) {
      const double ls = __hip_atomic_load(loss_sum, __ATOMIC_RELAXED,
                                          __HIP_MEMORY_SCOPE_AGENT);
      out[(size_t)VQ_N * VQ_D] =
          (float)(1.25 * ls / ((double)VQ_N * (double)VQ_D));
      out[(size_t)VQ_N * VQ_D + 1] = (float)exp(-part[0]);
    }
  }
}

extern "C" void kernel_launch(void* const* d_in, const int* in_sizes, int n_in,
                              void* d_out, int out_size, void* d_ws,
                              size_t ws_size, hipStream_t stream) {
  const float* X = (const float*)d_in[0];
  const float* E = (const float*)d_in[1];
  float* out = (float*)d_out;

  char* ws = (char*)d_ws;
  signed char* Ebs = (signed char*)ws;                   // 2 MB
  int* en_int = (int*)(ws + 2097152);                    // 32 KB
  double* loss_sum = (double*)(ws + 2129920);            // 64 B
  int* hist = (int*)(ws + 2129984);                      // 32 KB
  unsigned int* ticket2 = (unsigned int*)(ws + 2162752); // 64 B
  unsigned int* tickrb = (unsigned int*)(ws + 2162816);  // 256 B
  unsigned long long* bestp =
      (unsigned long long*)(ws + 2163072);               // 1 MB (N x 8)

  vq_pack<<<512, 256, 0, stream>>>(E, Ebs, en_int, loss_sum, hist, tickrb,
                                   ticket2);
  vq_score<<<512, 256, 0, stream>>>(X, Ebs, en_int, E, out, loss_sum, hist,
                                    tickrb, ticket2, bestp, out);
}

// Round 12
// 166.292 us; speedup vs baseline: 1.4838x; 1.4838x over previous
//
#include <hip/hip_runtime.h>

// VectorQuantizer: x [16,1024,256] f32, E [8192,256] f32.
// Outputs concat: quantized_st (4194304 f32) | loss (1) | perplexity (1).
//
// Round 12: r10 skeleton (separate kernels — r11 proved fusion-with-wait
// convoys, 183us), with:
//  1. phase-1 at 4 waves/SIMD: 512-thread blocks, 256 rows (af[2][4]=32 regs
//     per wave), 8 kparts, chunk=128 codes (2x32KB LDS, 2 blocks/CU).
//  2. atomicMin(u64) merge into bestfin[N] (orderable(s)<<32|code; u64-min ==
//     (s,code) lexicographic == np.argmin tie-break) — no partial array,
//     no reduce in the tail.
//  3. MLP gather: wave owns 8 consecutive rows, one 8-lane bestfin load,
//     8 independent gather chains. Ticket finalize unchanged.

#define VQ_N 16384
#define VQ_D 256
#define VQ_K 8192

typedef __attribute__((ext_vector_type(4))) int i32x4;

#define SX 22.0f
#define SEF 1040384.0f               // 127 * 8192
#define ENSCALE 11444224.0           // SX * SEF / 2

__device__ inline int q8(float f, float scale) {
  return __float2int_rn(fminf(fmaxf(f * scale, -127.f), 127.f));
}

__device__ inline void gl_lds16(const void* g, void* l) {
  __builtin_amdgcn_global_load_lds(
      (const __attribute__((address_space(1))) unsigned int*)g,
      (__attribute__((address_space(3))) unsigned int*)l, 16, 0, 0);
}
__device__ inline void gl_lds4(const void* g, void* l) {
  __builtin_amdgcn_global_load_lds(
      (const __attribute__((address_space(1))) unsigned int*)g,
      (__attribute__((address_space(3))) unsigned int*)l, 4, 0, 0);
}

// ---- pack E -> i8 swizzled + en_int + init bestfin/hist/ticket/loss ----
// B layout: group g (16 codes): off = g*4096 + kchunk*256 + code_local*16 + j,
// k = kchunk*16 + j. Pack thread = (code, kchunk).
__global__ __launch_bounds__(256) void vq_pack(
    const float* __restrict__ E, signed char* __restrict__ Ebs,
    int* __restrict__ en_int, double* __restrict__ loss_sum,
    int* __restrict__ hist, unsigned long long* __restrict__ bestfin,
    unsigned int* __restrict__ ticket) {
  const int gid = blockIdx.x * 256 + threadIdx.x;  // 0..131071
  if (gid < VQ_K) hist[gid] = 0;
  if (gid < VQ_N) bestfin[gid] = ~0ULL;
  if (gid == 0) { *loss_sum = 0.0; *ticket = 0u; }
  const int code = gid >> 4;
  const int chunk = gid & 15;
  const float* src = E + (size_t)code * VQ_D + chunk * 16;
  double s = 0.0;
  unsigned int w[4];
#pragma unroll
  for (int v = 0; v < 4; ++v) {
    const float4 f = *(const float4*)(src + v * 4);
    s += (double)f.x * f.x + (double)f.y * f.y + (double)f.z * f.z +
         (double)f.w * f.w;
    const int q0 = q8(f.x, SEF), q1 = q8(f.y, SEF);
    const int q2 = q8(f.z, SEF), q3 = q8(f.w, SEF);
    w[v] = (unsigned)(q0 & 255) | ((unsigned)(q1 & 255) << 8) |
           ((unsigned)(q2 & 255) << 16) | ((unsigned)(q3 & 255) << 24);
  }
  const size_t off =
      ((size_t)(code >> 4) * 16 + chunk) * 256 + (size_t)(code & 15) * 16;
  *(uint4*)(Ebs + off) = make_uint4(w[0], w[1], w[2], w[3]);
#pragma unroll
  for (int m = 1; m <= 8; m <<= 1) s += __shfl_xor(s, m, 64);
  if (chunk == 0) en_int[code] = (int)__double2int_rn(s * ENSCALE);
}

// ---- i8 MFMA score, LDS-staged B, atomicMin merge ----
// Grid 512 x 512 threads. Block (rowblk = b>>3, q = b&7): 256 rows x 1024
// codes. 8 waves, 32 rows each (af[2][4]). Chunk = 128 codes (32 KB), x8.
__global__ __launch_bounds__(512, 2) void vq_score(
    const float* __restrict__ X, const signed char* __restrict__ Ebs,
    const int* __restrict__ en_int,
    unsigned long long* __restrict__ bestfin) {
  __shared__ __align__(16) signed char bbuf[2][32768];  // 2 x 128-code chunks
  __shared__ __align__(16) int enl[1024];

  const int tid = threadIdx.x;           // 0..511
  const int wave = tid >> 6;             // 0..7
  const int lane = tid & 63;
  const int quad = lane >> 4;
  const int c15 = lane & 15;
  const int rowblk = blockIdx.x >> 3;
  const int q = blockIdx.x & 7;
  const int r0 = rowblk * 256;
  const int qcode = q * 1024;
  const signed char* ebase = Ebs + (size_t)qcode * 256;

  // Stage en (4 KB) + first B chunk (32 KB). Dest = wave-uniform + lane*size.
  {
    const int* ens = en_int + qcode;
#pragma unroll
    for (int j = 0; j < 2; ++j)
      gl_lds4(ens + j * 512 + wave * 64 + lane,
              enl + j * 512 + wave * 64 + lane);
#pragma unroll
    for (int j = 0; j < 4; ++j)
      gl_lds16(ebase + j * 8192 + wave * 1024 + lane * 16,
               &bbuf[0][j * 8192 + wave * 1024 + lane * 16]);
  }

  // A fragments: af[t][m], row r0 + wave*32 + t*16 + c15, k = m*64+quad*16+j.
  i32x4 af[2][4];
#pragma unroll
  for (int t = 0; t < 2; ++t) {
    const float* xr =
        X + (size_t)(r0 + wave * 32 + t * 16 + c15) * VQ_D + quad * 16;
#pragma unroll
    for (int m = 0; m < 4; ++m) {
      const float* p = xr + m * 64;
      i32x4 pk;
#pragma unroll
      for (int v = 0; v < 4; ++v) {
        const float4 f = *(const float4*)(p + v * 4);
        pk[v] = (q8(f.x, SX) & 255) | ((q8(f.y, SX) & 255) << 8) |
                ((q8(f.z, SX) & 255) << 16) | ((q8(f.w, SX) & 255) << 24);
      }
      af[t][m] = pk;
    }
  }

  int best_p[2][4];
#pragma unroll
  for (int t = 0; t < 2; ++t)
#pragma unroll
    for (int r = 0; r < 4; ++r) best_p[t][r] = 0x7fffffff;

#pragma unroll 1
  for (int c = 0; c < 8; ++c) {
    __syncthreads();  // chunk c staged; prior reads of other buffer done
    if (c + 1 < 8) {
      const signed char* bs = ebase + (c + 1) * 32768;
#pragma unroll
      for (int j = 0; j < 4; ++j)
        gl_lds16(bs + j * 8192 + wave * 1024 + lane * 16,
                 &bbuf[(c + 1) & 1][j * 8192 + wave * 1024 + lane * 16]);
    }
    const signed char* cb = &bbuf[c & 1][0];
#pragma unroll
    for (int g = 0; g < 8; ++g) {
      i32x4 bfr[4];
#pragma unroll
      for (int m = 0; m < 4; ++m)
        bfr[m] = *(const i32x4*)(cb + g * 4096 + m * 1024 + lane * 16);
      const int gidx = c * 8 + g;  // 0..63
      // p = s*64 + gidx = (en<<6 + gidx) - (dot<<6); exact int, |p| < 2^31.
      const int enp = (enl[gidx * 16 + c15] << 6) + gidx;
      i32x4 a0 = {0, 0, 0, 0}, a1 = {0, 0, 0, 0};
#pragma unroll
      for (int m = 0; m < 4; ++m) {
        a0 = __builtin_amdgcn_mfma_i32_16x16x64_i8(af[0][m], bfr[m], a0, 0, 0, 0);
        a1 = __builtin_amdgcn_mfma_i32_16x16x64_i8(af[1][m], bfr[m], a1, 0, 0, 0);
      }
#pragma unroll
      for (int r = 0; r < 4; ++r) {
        best_p[0][r] = min(best_p[0][r], enp - (a0[r] << 6));
        best_p[1][r] = min(best_p[1][r], enp - (a1[r] << 6));
      }
    }
  }

  // decode, u64 min over the 16 code-lanes, atomicMin into bestfin
#pragma unroll
  for (int t = 0; t < 2; ++t)
#pragma unroll
    for (int r = 0; r < 4; ++r) {
      const int p = best_p[t][r];
      const int s = p >> 6;  // arithmetic shift: floor(p/64) == s
      const int code = qcode + (p & 63) * 16 + c15;
      unsigned long long v =
          ((unsigned long long)((unsigned)s ^ 0x80000000u) << 32) |
          (unsigned)code;
#pragma unroll
      for (int m = 1; m <= 8; m <<= 1) {
        const unsigned long long ov = __shfl_xor(v, m, 64);
        if (ov < v) v = ov;
      }
      if (c15 == 0) {
        const int row = r0 + wave * 32 + t * 16 + quad * 4 + r;
        atomicMin(&bestfin[row], v);
      }
    }
}

// ---- gather + loss + hist + (last block) finalize ----
// 512 blocks x 256. Wave gw owns rows [gw*8, gw*8+8): one 8-lane bestfin
// load, 8 independent gather chains.
__global__ __launch_bounds__(256) void vq_gather_fin(
    const float* __restrict__ X, const float* __restrict__ E,
    const unsigned long long* __restrict__ bestfin, float* __restrict__ outq,
    double* __restrict__ loss_sum, int* __restrict__ hist,
    unsigned int* __restrict__ ticket, float* __restrict__ out) {
  __shared__ double wsum[4];
  __shared__ double part[256];
  __shared__ int sdone;
  const int wid = threadIdx.x >> 6;
  const int lane = threadIdx.x & 63;
  const int gw = blockIdx.x * 4 + wid;  // 0..2047
  const int row0 = gw * 8;

  const unsigned long long v = (lane < 8) ? bestfin[row0 + lane] : 0ULL;
  int ks[8];
#pragma unroll
  for (int j = 0; j < 8; ++j)
    ks[j] = (int)(__shfl(v, j, 64) & 0xFFFFFFFFu);

  if (lane == 0) {
#pragma unroll
    for (int j = 0; j < 8; ++j)
      __hip_atomic_fetch_add(&hist[ks[j]], 1, __ATOMIC_RELAXED,
                             __HIP_MEMORY_SCOPE_AGENT);
  }

  double acc = 0.0;
#pragma unroll
  for (int j = 0; j < 8; ++j) {
    const int row = row0 + j;
    const int k = ks[j];
    const float4 qv = *(const float4*)(E + (size_t)k * VQ_D + lane * 4);
    const float4 xv = *(const float4*)(X + (size_t)row * VQ_D + lane * 4);
    *(float4*)(outq + (size_t)row * VQ_D + lane * 4) = qv;
    const double dx = (double)qv.x - xv.x, dy = (double)qv.y - xv.y;
    const double dz = (double)qv.z - xv.z, dw = (double)qv.w - xv.w;
    acc += dx * dx + dy * dy + dz * dz + dw * dw;
  }
#pragma unroll
  for (int off = 32; off > 0; off >>= 1) acc += __shfl_down(acc, off, 64);
  if (lane == 0) wsum[wid] = acc;
  __syncthreads();
  if (threadIdx.x == 0) {
    atomicAdd(loss_sum, wsum[0] + wsum[1] + wsum[2] + wsum[3]);
    __threadfence();
    const unsigned int old = __hip_atomic_fetch_add(
        ticket, 1u, __ATOMIC_ACQ_REL, __HIP_MEMORY_SCOPE_AGENT);
    sdone = (old == 511u) ? 1 : 0;
  }
  __syncthreads();

  if (sdone) {  // last block: all hist/loss atomics visible
    const int tx = threadIdx.x;
    double s = 0.0;
    for (int k = tx; k < VQ_K; k += 256) {
      const int c = __hip_atomic_load(&hist[k], __ATOMIC_RELAXED,
                                      __HIP_MEMORY_SCOPE_AGENT);
      if (c > 0) {
        const double pr = (double)c * (1.0 / (double)VQ_N);
        s += pr * log(pr + 1e-10);
      }
    }
    part[tx] = s;
    __syncthreads();
    for (int off = 128; off > 0; off >>= 1) {
      if (tx < off) part[tx] += part[tx + off];
      __syncthreads();
    }
    if (tx == 0) {
      const double ls = __hip_atomic_load(loss_sum, __ATOMIC_RELAXED,
                                          __HIP_MEMORY_SCOPE_AGENT);
      out[(size_t)VQ_N * VQ_D] =
          (float)(1.25 * ls / ((double)VQ_N * (double)VQ_D));
      out[(size_t)VQ_N * VQ_D + 1] = (float)exp(-part[0]);
    }
  }
}

extern "C" void kernel_launch(void* const* d_in, const int* in_sizes, int n_in,
                              void* d_out, int out_size, void* d_ws,
                              size_t ws_size, hipStream_t stream) {
  const float* X = (const float*)d_in[0];
  const float* E = (const float*)d_in[1];
  float* out = (float*)d_out;

  char* ws = (char*)d_ws;
  signed char* Ebs = (signed char*)ws;                   // 2 MB
  int* en_int = (int*)(ws + 2097152);                    // 32 KB
  double* loss_sum = (double*)(ws + 2129920);            // 64 B
  int* hist = (int*)(ws + 2129984);                      // 32 KB
  unsigned int* ticket = (unsigned int*)(ws + 2162752);  // 64 B
  unsigned long long* bestfin =
      (unsigned long long*)(ws + 2162816);               // 128 KB

  vq_pack<<<512, 256, 0, stream>>>(E, Ebs, en_int, loss_sum, hist, bestfin,
                                   ticket);
  vq_score<<<512, 512, 0, stream>>>(X, Ebs, en_int, bestfin);
  vq_gather_fin<<<512, 256, 0, stream>>>(X, E, bestfin, out, loss_sum, hist,
                                         ticket, out);
}